// Round 15
// baseline (6339.400 us; speedup 1.0000x reference)
//
#include <hip/hip_runtime.h>
#include <hip/hip_bf16.h>
#include <stdint.h>

#define EPSV 1e-12f
#define NB 32
#define DD 1024
#define QQ 64
#define EE 384
#define HH 384
#define NW 12    // workgroups per (corpus,dir) recurrence group
#define CH 256   // doc chunk length (steps) per k_xp/k_rec launch

typedef __attribute__((ext_vector_type(4))) float f32x4;
typedef __attribute__((ext_vector_type(8))) __bf16 bf16x8;
typedef __attribute__((ext_vector_type(4))) unsigned short u16x4;
typedef __attribute__((ext_vector_type(4))) int i32x4;
typedef unsigned short u16;

static __device__ __forceinline__ u16 f2bf(float f) {
  union { float f; uint32_t u; } v; v.f = f;
  uint32_t u = v.u;
  return (u16)((u + 0x7fffu + ((u >> 16) & 1u)) >> 16);  // RNE
}

static __device__ __forceinline__ f32x4 MFMA(bf16x8 a, bf16x8 b, f32x4 c) {
  return __builtin_amdgcn_mfma_f32_16x16x32_bf16(a, b, c, 0, 0, 0);
}

static __device__ __forceinline__ bf16x8 ldw8(const float* p) {
  float4 a = *(const float4*)p;
  float4 b = *(const float4*)(p + 4);
  union { u16 e[8]; bf16x8 v; } u;
  u.e[0] = f2bf(a.x); u.e[1] = f2bf(a.y); u.e[2] = f2bf(a.z); u.e[3] = f2bf(a.w);
  u.e[4] = f2bf(b.x); u.e[5] = f2bf(b.y); u.e[6] = f2bf(b.z); u.e[7] = f2bf(b.w);
  return u.v;
}

// device-scope (L3-coherent) store — proven R3/R7/R12/R14
static __device__ __forceinline__ void st_short_sc(u16* p, u16 v) {
  asm volatile("global_store_short %0, %1, off sc1" :: "v"(p), "v"((uint32_t)v) : "memory");
}
// 12-fragment h load (0..704 byte offsets, stride 64) + drain, ONE asm block.
// Used as a DATA POLL: caller checks for 0xFFFF sentinels (bf16 NaN, unreachable for GRU h).
static __device__ __forceinline__ void ld_h12(const u16* p,
    i32x4& d0, i32x4& d1, i32x4& d2, i32x4& d3, i32x4& d4, i32x4& d5,
    i32x4& d6, i32x4& d7, i32x4& d8, i32x4& d9, i32x4& d10, i32x4& d11) {
  asm volatile(
      "global_load_dwordx4 %0, %12, off sc1\n\t"
      "global_load_dwordx4 %1, %12, off offset:64 sc1\n\t"
      "global_load_dwordx4 %2, %12, off offset:128 sc1\n\t"
      "global_load_dwordx4 %3, %12, off offset:192 sc1\n\t"
      "global_load_dwordx4 %4, %12, off offset:256 sc1\n\t"
      "global_load_dwordx4 %5, %12, off offset:320 sc1\n\t"
      "global_load_dwordx4 %6, %12, off offset:384 sc1\n\t"
      "global_load_dwordx4 %7, %12, off offset:448 sc1\n\t"
      "global_load_dwordx4 %8, %12, off offset:512 sc1\n\t"
      "global_load_dwordx4 %9, %12, off offset:576 sc1\n\t"
      "global_load_dwordx4 %10, %12, off offset:640 sc1\n\t"
      "global_load_dwordx4 %11, %12, off offset:704 sc1\n\t"
      "s_waitcnt vmcnt(0)"
      : "=&v"(d0), "=&v"(d1), "=&v"(d2), "=&v"(d3), "=&v"(d4), "=&v"(d5),
        "=&v"(d6), "=&v"(d7), "=&v"(d8), "=&v"(d9), "=&v"(d10), "=&v"(d11)
      : "v"(p) : "memory");
}

// ---------------- embedding gather ----------------
__global__ __launch_bounds__(256) void k_emb(const int* __restrict__ doc, const int* __restrict__ qry,
                                             const float* __restrict__ emb, u16* __restrict__ embx) {
  int i = blockIdx.x * 256 + threadIdx.x;
  int row = i / 96, e4 = i - row * 96;
  int tok = (row < NB * DD) ? doc[row] : qry[row - NB * DD];
  float4 v = ((const float4*)(emb + (size_t)tok * EE))[e4];
  u16x4 o; o.x = f2bf(v.x); o.y = f2bf(v.y); o.z = f2bf(v.z); o.w = f2bf(v.w);
  *(u16x4*)(embx + (size_t)row * EE + e4 * 4) = o;
}

// ---------------- xp = x @ W_ih^T + bias, f32, chunked (R4/R12-proven, verbatim) ----------------
__global__ __launch_bounds__(512, 2) void k_xp(
    const u16* __restrict__ embx, const int* __restrict__ doc_lens, const int* __restrict__ q_lens,
    const float* __restrict__ w_ih_f, const float* __restrict__ b_ih_f, const float* __restrict__ b_hh_f,
    const float* __restrict__ w_ih_b, const float* __restrict__ b_ih_b, const float* __restrict__ b_hh_b,
    float* __restrict__ xpd, float* __restrict__ xpq, int cbase) {
  __shared__ int lensh[32];
  const int gx = blockIdx.x;
  int corpus, d2, jblk, tch;
  if (gx < 48) { corpus = 0; d2 = gx / 24; int rem = gx % 24; jblk = rem / 4; tch = rem % 4; }
  else { corpus = 1; int g2 = gx - 48; d2 = g2 / 6; jblk = g2 % 6; tch = 0; }
  const int T = corpus ? QQ : DD;
  const int* lens = corpus ? q_lens : doc_lens;
  const float* w_ih = d2 ? w_ih_b : w_ih_f;
  const float* b_ih = d2 ? b_ih_b : b_ih_f;
  const float* b_hh = d2 ? b_hh_b : b_hh_f;
  const u16* exb = embx + (corpus ? (size_t)NB * DD * EE : 0);
  float* xpg = corpus ? (xpq + (size_t)d2 * QQ * 36864) : (xpd + (size_t)d2 * CH * 36864);
  const int tid = threadIdx.x;
  if (tid < 32) lensh[tid] = lens[tid];
  __syncthreads();
  const int lane = tid & 63, wv = tid >> 6;
  const int wslot = wv >> 1, mt = wv & 1;
  const int col = lane & 15, khi = lane >> 4;
  const int jg = jblk * 64 + wslot * 16 + col;
  const float br = b_ih[jg] + b_hh[jg];
  const float bz = b_ih[384 + jg] + b_hh[384 + jg];
  const float bn = b_ih[768 + jg];
  bf16x8 Wr[12], Wz[12], Wn[12];
#pragma unroll
  for (int ks = 0; ks < 12; ++ks) {
    Wr[ks] = ldw8(w_ih + (size_t)jg * 384 + ks * 32 + khi * 8);
    Wz[ks] = ldw8(w_ih + (size_t)(384 + jg) * 384 + ks * 32 + khi * 8);
    Wn[ks] = ldw8(w_ih + (size_t)(768 + jg) * 384 + ks * 32 + khi * 8);
  }
  const int b_a = mt * 16 + col;
  const int lenb = lensh[b_a];
  const int bh0 = mt * 16 + khi * 4;
  for (int tt = 0; tt < 64; ++tt) {
    const int s_lc = tch * 64 + tt;
    const int s_g = corpus ? s_lc : (cbase + s_lc);
    const int trow = d2 ? ((s_g < lenb) ? (lenb - 1 - s_g) : s_g) : s_g;
    const u16* ap = exb + ((size_t)b_a * T + trow) * EE + khi * 8;
    bf16x8 A[12];
#pragma unroll
    for (int ks = 0; ks < 12; ++ks) A[ks] = *(const bf16x8*)(ap + ks * 32);
    f32x4 ar{0.f, 0.f, 0.f, 0.f}, az = ar, an = ar;
#pragma unroll
    for (int ks = 0; ks < 12; ++ks) {
      ar = MFMA(A[ks], Wr[ks], ar);
      az = MFMA(A[ks], Wz[ks], az);
      an = MFMA(A[ks], Wn[ks], an);
    }
    float* op = xpg + (size_t)s_lc * 36864 + (size_t)jg * 32 + bh0;
    f32x4 o0{ar[0] + br, ar[1] + br, ar[2] + br, ar[3] + br};
    f32x4 o1{az[0] + bz, az[1] + bz, az[2] + bz, az[3] + bz};
    f32x4 o2{an[0] + bn, an[1] + bn, an[2] + bn, an[3] + bn};
    *(f32x4*)op = o0;
    *(f32x4*)(op + 384 * 32) = o1;
    *(f32x4*)(op + 768 * 32) = o2;
  }
}

// ---------------- BiGRU recurrence: xp-precompute (R12 math) + sentinel data-poll (R14 protocol) ----------------
// h_all[grp][slot 0..T][b][j] bf16, sentinel 0xFF-armed per launch. Producer: 4 fire-and-forget
// sc1 stores into slot s+1 (the data IS the flag). Consumer: polls its 12 A-fragments of slot s.
// No tags, no drains, no init barrier. Per-step chain = store-land + observe + 36 MFMA + gates.
__global__ __launch_bounds__(256) void k_rec(
    const float* __restrict__ xpd, const float* __restrict__ xpq,
    const int* __restrict__ doc_lens, const int* __restrict__ q_lens,
    const float* __restrict__ w_hh_f, const float* __restrict__ b_hh_f,
    const float* __restrict__ w_hh_b, const float* __restrict__ b_hh_b,
    u16* __restrict__ doc_h, u16* __restrict__ q_h,
    u16* __restrict__ h_all, float* __restrict__ h_state, int cbase, int first) {
  __shared__ u16 wfrag[36864];       // h-part weights only, R12 fragment layout (72 KB)
  __shared__ int lensh[32];

  const int grp = blockIdx.x / NW;   // chunks>0 launch 24 blocks -> grp in {0,1} (doc only)
  const int wg = blockIdx.x - grp * NW;
  const int corpus = grp >> 1, dir = grp & 1;
  const int T = corpus ? QQ : DD;
  const int nst = corpus ? QQ : CH;
  const int* lens = corpus ? q_lens : doc_lens;
  const float* w_hh = dir ? w_hh_b : w_hh_f;
  const float* b_hh = dir ? b_hh_b : b_hh_f;
  u16* out = corpus ? q_h : doc_h;
  const float* xpg = corpus ? (xpq + (size_t)dir * QQ * 36864) : (xpd + (size_t)dir * CH * 36864);
  u16* ha = h_all + (size_t)grp * ((DD + 1) * NB * HH);
  const int tid = threadIdx.x;

  if (tid < 32) lensh[tid] = lens[tid];
  // pack h-part weight slice (R12-identical layout)
  for (int idx = tid; idx < 36864; idx += 256) {
    int nt = idx / 6144;
    int rem = idx - nt * 6144;
    int ks = rem >> 9;
    int le = rem & 511;
    int lane_ = le >> 3, i = le & 7;
    int g = nt >> 1, js_ = nt & 1;
    int colw = lane_ & 15, khiw = lane_ >> 4;
    int k = ks * 32 + (lane_ >> 4) * 8 + i;
    int rowg = g * 384 + wg * 32 + js_ * 16 + colw;
    (void)khiw;
    wfrag[idx] = f2bf(w_hh[(size_t)rowg * 384 + k]);
  }
  if (first) {
    // write zero state into slot 0 (own dim slice, all batches) — fire-and-forget;
    // consumers' sentinel poll provides the ordering (no barrier needed)
    for (int idx = tid; idx < 1024; idx += 256) {
      int b = idx >> 5, jl_ = idx & 31;
      st_short_sc(ha + (size_t)b * HH + wg * 32 + jl_, (u16)0);
    }
  }
  __syncthreads();

  const int lane = tid & 63, wv = tid >> 6;
  const int mt = wv >> 1, js = wv & 1;
  const int col = lane & 15, khi = lane >> 4;
  const int jg = wg * 32 + js * 16 + col;          // hidden dim this lane produces
  const float bias_hn = b_hh[768 + jg];
  const int b_x = mt * 16 + col;                   // A-fragment batch row
  const int bh0 = mt * 16 + khi * 4;               // accumulator batch base
  int len_h[4];
#pragma unroll
  for (int r = 0; r < 4; ++r) len_h[r] = lensh[bh0 + r];
  u16* outp = out + (size_t)dir * HH + jg;
  f32x4 hprev;
#pragma unroll
  for (int r = 0; r < 4; ++r)
    hprev[r] = first ? 0.f : h_state[(size_t)grp * 12288 + (size_t)jg * 32 + (bh0 + r)];

  auto load_xp = [&](f32x4* x, int sl) {
    const float* xs = xpg + (size_t)sl * 36864;
#pragma unroll
    for (int g = 0; g < 3; ++g)
      x[g] = *(const f32x4*)(xs + ((size_t)(g * 384 + jg)) * 32 + bh0);
  };

  f32x4 xpA[3], xpB[3];
  load_xp(xpA, 0);

  auto step = [&](int sl, f32x4* xc, f32x4* xn) {
    const int s = cbase + sl;
    // DATA-POLL slot s: the successful iteration's loads ARE the A-fragments
    const u16* ahp = ha + (size_t)s * (NB * HH) + (size_t)b_x * HH + khi * 8;
    i32x4 a0, a1, a2, a3, a4, a5, a6, a7, a8, a9, a10, a11;
    while (true) {
      ld_h12(ahp, a0, a1, a2, a3, a4, a5, a6, a7, a8, a9, a10, a11);
      uint32_t bad = 0;
      auto chk = [&](const i32x4& d) {
#pragma unroll
        for (int k = 0; k < 4; ++k) {
          uint32_t u = (uint32_t)d[k];
          bad |= ((u & 0xFFFFu) == 0xFFFFu);
          bad |= ((u >> 16) == 0xFFFFu);
        }
      };
      chk(a0); chk(a1); chk(a2); chk(a3); chk(a4); chk(a5);
      chk(a6); chk(a7); chk(a8); chk(a9); chk(a10); chk(a11);
      if (__all(bad == 0)) break;
      __builtin_amdgcn_s_sleep(1);
    }
    __builtin_amdgcn_sched_barrier(0);
    // 36 MFMA (h-part only, K=384) — R12-identical order
    i32x4 areg[12] = {a0, a1, a2, a3, a4, a5, a6, a7, a8, a9, a10, a11};
    f32x4 acc_r{0.f, 0.f, 0.f, 0.f};
    f32x4 acc_z = acc_r, acc_nh = acc_r;
#pragma unroll
    for (int ks = 0; ks < 12; ++ks) {
      bf16x8 af = __builtin_bit_cast(bf16x8, areg[ks]);
      bf16x8 br = *(const bf16x8*)&wfrag[((js) * 12 + ks) * 512 + lane * 8];
      bf16x8 bz = *(const bf16x8*)&wfrag[((2 + js) * 12 + ks) * 512 + lane * 8];
      bf16x8 bn = *(const bf16x8*)&wfrag[((4 + js) * 12 + ks) * 512 + lane * 8];
      acc_r = MFMA(af, br, acc_r);
      acc_z = MFMA(af, bz, acc_z);
      acc_nh = MFMA(af, bn, acc_nh);
    }
    // gates (R12-identical) + fire-and-forget h stores into slot s+1 (no drain, no tag)
    u16 hq[4];
    u16* wslice = ha + (size_t)(s + 1) * (NB * HH);
#pragma unroll
    for (int r = 0; r < 4; ++r) {
      const int b = bh0 + r;
      float rg = 1.f / (1.f + __expf(-(acc_r[r] + xc[0][r])));
      float zg = 1.f / (1.f + __expf(-(acc_z[r] + xc[1][r])));
      float ng = tanhf(xc[2][r] + rg * (acc_nh[r] + bias_hn));
      float hn = (1.f - zg) * ng + zg * hprev[r];
      hprev[r] = hn;
      hq[r] = f2bf(hn);
      st_short_sc(wslice + (size_t)b * HH + jg, hq[r]);
    }
    // slow ops last: xp prefetch + scattered output stores — drained in next poll's idle window
    load_xp(xn, (sl + 1 < nst) ? (sl + 1) : sl);
#pragma unroll
    for (int r = 0; r < 4; ++r) {
      const int b = bh0 + r;
      const int len = len_h[r];
      const int tro = dir ? ((s < len) ? (len - 1 - s) : s) : s;
      outp[((size_t)b * T + tro) * (2 * HH)] = hq[r];
    }
  };

  for (int sl = 0; sl < nst; sl += 2) {
    step(sl, xpA, xpB);
    step(sl + 1, xpB, xpA);
  }
  // carry f32 state to next chunk (flushed at kernel end)
#pragma unroll
  for (int r = 0; r < 4; ++r)
    h_state[(size_t)grp * 12288 + (size_t)jg * 32 + (bh0 + r)] = hprev[r];
}

// ---------------- scores + row (q-axis) stats ----------------
__global__ __launch_bounds__(256) void k_scores(
    const u16* __restrict__ doc_h, const u16* __restrict__ q_h,
    const int* __restrict__ doc_lens, const int* __restrict__ q_lens,
    float* __restrict__ SM, float* __restrict__ rowmax, float* __restrict__ rowsum) {
  const int b = blockIdx.x >> 4, dblk = blockIdx.x & 15;
  const int tid = threadIdx.x, lane = tid & 63, wv = tid >> 6;
  const int col = lane & 15, khi = lane >> 4;
  const int dlen = doc_lens[b], qlen = q_lens[b];
  const u16* dp = doc_h + ((size_t)(b * DD + dblk * 64 + wv * 16 + col)) * (2 * HH) + khi * 8;
  const u16* qp = q_h + (size_t)b * QQ * (2 * HH);
  f32x4 acc[4];
#pragma unroll
  for (int nt = 0; nt < 4; ++nt) acc[nt] = f32x4{0.f, 0.f, 0.f, 0.f};
  for (int ks = 0; ks < 24; ++ks) {
    bf16x8 av = *(const bf16x8*)(dp + ks * 32);
#pragma unroll
    for (int nt = 0; nt < 4; ++nt) {
      bf16x8 bv = *(const bf16x8*)(qp + (size_t)(nt * 16 + col) * (2 * HH) + ks * 32 + khi * 8);
      acc[nt] = MFMA(av, bv, acc[nt]);
    }
  }
  const int d0 = dblk * 64 + wv * 16 + khi * 4;
  float* smb = SM + (size_t)b * DD * QQ;
#pragma unroll
  for (int r = 0; r < 4; ++r) {
    const int d = d0 + r;
    const bool dv = d < dlen;
    float v[4];
#pragma unroll
    for (int nt = 0; nt < 4; ++nt) {
      const int q = nt * 16 + col;
      v[nt] = (dv && q < qlen) ? acc[nt][r] : 0.f;
      smb[(size_t)d * QQ + q] = v[nt];
    }
    float mx = fmaxf(fmaxf(v[0], v[1]), fmaxf(v[2], v[3]));
#pragma unroll
    for (int off = 1; off < 16; off <<= 1) mx = fmaxf(mx, __shfl_xor(mx, off, 64));
    float sm = 0.f;
#pragma unroll
    for (int nt = 0; nt < 4; ++nt) {
      const int q = nt * 16 + col;
      if (dv && q < qlen) sm += __expf(v[nt] - mx);
    }
#pragma unroll
    for (int off = 1; off < 16; off <<= 1) sm += __shfl_xor(sm, off, 64);
    if (col == 0) { rowmax[b * DD + d] = mx; rowsum[b * DD + d] = sm; }
  }
}

// ---------------- column (d-axis) stats + beta_aver ----------------
__global__ __launch_bounds__(256) void k_cols(
    const float* __restrict__ SM, const float* __restrict__ rowmax, const float* __restrict__ rowsum,
    const int* __restrict__ doc_lens, const int* __restrict__ q_lens,
    float* __restrict__ colmax, float* __restrict__ colsum, float* __restrict__ bav) {
  const int b = blockIdx.x, tid = threadIdx.x;
  const int q = tid & 63, dg = tid >> 6;
  __shared__ float red[4][64];
  __shared__ float cmx[64];
  const float* smb = SM + (size_t)b * DD * QQ;
  float cm = -3.0e38f;
  for (int d = dg; d < DD; d += 4) cm = fmaxf(cm, smb[(size_t)d * QQ + q]);
  red[dg][q] = cm;
  __syncthreads();
  if (tid < 64) cmx[tid] = fmaxf(fmaxf(red[0][tid], red[1][tid]), fmaxf(red[2][tid], red[3][tid]));
  __syncthreads();
  const int dlen = doc_lens[b];
  const bool qv = q < q_lens[b];
  const float cmq = cmx[q];
  float cs = 0.f, ba = 0.f;
  for (int d = dg; d < DD; d += 4) {
    if (qv && d < dlen) {
      float v = smb[(size_t)d * QQ + q];
      cs += __expf(v - cmq);
      ba += __expf(v - rowmax[b * DD + d]) / (rowsum[b * DD + d] + EPSV);
    }
  }
  __syncthreads();
  red[dg][q] = cs;
  __syncthreads();
  float cst = 0.f;
  if (tid < 64) cst = red[0][tid] + red[1][tid] + red[2][tid] + red[3][tid];
  __syncthreads();
  red[dg][q] = ba;
  __syncthreads();
  if (tid < 64) {
    float bat = red[0][tid] + red[1][tid] + red[2][tid] + red[3][tid];
    colmax[b * QQ + tid] = cmx[tid];
    colsum[b * QQ + tid] = cst;
    bav[b * QQ + tid] = bat / (float)dlen;
  }
}

// ---------------- s = alpha @ beta_aver, probs, vocab scatter ----------------
__global__ __launch_bounds__(256) void k_s(
    const float* __restrict__ SM, const float* __restrict__ colmax, const float* __restrict__ colsum,
    const float* __restrict__ bav, const int* __restrict__ doc_lens, const int* __restrict__ q_lens,
    const int* __restrict__ documents, const int* __restrict__ answers,
    float* __restrict__ sc, float* __restrict__ cnt_tok, float* __restrict__ dout) {
  const int b = blockIdx.x >> 2, dblk = blockIdx.x & 3;
  const int tid = threadIdx.x;
  __shared__ float cm[64], cs[64], bv[64];
  __shared__ int qm[64];
  if (tid < 64) {
    cm[tid] = colmax[b * QQ + tid];
    cs[tid] = colsum[b * QQ + tid];
    bv[tid] = bav[b * QQ + tid];
    qm[tid] = (tid < q_lens[b]) ? 1 : 0;
  }
  __syncthreads();
  const int d = dblk * 256 + tid;
  const bool dv = d < doc_lens[b];
  const float* smr = SM + ((size_t)b * DD + d) * QQ;
  float sd = 0.f;
#pragma unroll
  for (int q = 0; q < 64; ++q) {
    float e = (dv && qm[q]) ? __expf(smr[q] - cm[q]) : 0.f;
    sd += e / (cs[q] + EPSV) * bv[q];
  }
  const int tok = documents[b * DD + d];
  if (tok == answers[b]) atomicAdd(&dout[b], sd);
  if (dv) {
    atomicAdd(&sc[(size_t)b * 50001 + tok], sd);
    atomicAdd(&cnt_tok[(size_t)b * 50001 + tok], 1.0f);
  }
}

// ---------------- first-max argmax over vocab ----------------
__global__ __launch_bounds__(256) void k_pred(
    const float* __restrict__ sc, const float* __restrict__ cnt_tok, float* __restrict__ dout) {
  const int b = blockIdx.x, tid = threadIdx.x;
  __shared__ float bvs[256];
  __shared__ int bis[256];
  float bvv = -3.0e38f;
  int bii = 0x7fffffff;
  for (int i = tid; i < 50001; i += 256) {
    if (cnt_tok[(size_t)b * 50001 + i] > 0.f) {
      float v = sc[(size_t)b * 50001 + i];
      if (v > bvv) { bvv = v; bii = i; }
    }
  }
  bvs[tid] = bvv;
  bis[tid] = bii;
  __syncthreads();
  for (int st = 128; st > 0; st >>= 1) {
    if (tid < st) {
      float v2 = bvs[tid + st];
      int i2 = bis[tid + st];
      if (v2 > bvs[tid] || (v2 == bvs[tid] && i2 < bis[tid])) { bvs[tid] = v2; bis[tid] = i2; }
    }
    __syncthreads();
  }
  if (tid == 0) dout[32 + b] = (float)bis[0];
}

extern "C" void kernel_launch(void* const* d_in, const int* in_sizes, int n_in,
                              void* d_out, int out_size, void* d_ws, size_t ws_size,
                              hipStream_t stream) {
  const int* documents = (const int*)d_in[0];
  const int* doc_lens = (const int*)d_in[1];
  const int* querys = (const int*)d_in[3];
  const int* query_lens = (const int*)d_in[4];
  const int* answers = (const int*)d_in[6];
  const float* emb = (const float*)d_in[7];
  const float* w_ih_f = (const float*)d_in[8];
  const float* w_hh_f = (const float*)d_in[9];
  const float* b_ih_f = (const float*)d_in[10];
  const float* b_hh_f = (const float*)d_in[11];
  const float* w_ih_b = (const float*)d_in[12];
  const float* w_hh_b = (const float*)d_in[13];
  const float* b_ih_b = (const float*)d_in[14];
  const float* b_hh_b = (const float*)d_in[15];
  float* dout = (float*)d_out;
  char* ws = (char*)d_ws;

  size_t o = 0;
  auto alloc = [&](size_t bytes) { size_t r = o; o += (bytes + 255) & ~(size_t)255; return r; };
  size_t o_embx = alloc((size_t)34816 * 384 * 2);
  size_t o_xpd  = alloc((size_t)2 * CH * 36864 * 4);           // 75.5 MB (doc chunk)
  size_t o_xpq  = alloc((size_t)2 * QQ * 36864 * 4);           // 18.9 MB (q full)
  size_t o_hall = alloc((size_t)4 * (DD + 1) * NB * HH * 2);   // 100.8 MB, sentinel-armed each launch
  size_t o_doch = alloc((size_t)NB * DD * 768 * 2);
  size_t o_qh   = alloc((size_t)NB * QQ * 768 * 2);
  size_t o_hst  = alloc((size_t)4 * HH * NB * 4);
  size_t o_SM   = alloc((size_t)NB * DD * QQ * 4);
  size_t o_rmax = alloc((size_t)NB * DD * 4);
  size_t o_rsum = alloc((size_t)NB * DD * 4);
  size_t o_cmax = alloc((size_t)NB * QQ * 4);
  size_t o_csum = alloc((size_t)NB * QQ * 4);
  size_t o_bav  = alloc((size_t)NB * QQ * 4);
  size_t o_sc   = alloc((size_t)NB * 50001 * 4);
  size_t o_ctk  = alloc((size_t)NB * 50001 * 4);
  (void)ws_size; (void)in_sizes; (void)n_in; (void)out_size;

  hipMemsetAsync(ws + o_hall, 0xFF, (size_t)4 * (DD + 1) * NB * HH * 2, stream);  // arm sentinels
  hipMemsetAsync(ws + o_sc, 0, (o_ctk - o_sc) + (size_t)NB * 50001 * 4, stream);
  hipMemsetAsync(d_out, 0, 64 * sizeof(float), stream);

  k_emb<<<13056, 256, 0, stream>>>(documents, querys, emb, (u16*)(ws + o_embx));
  for (int c = 0; c < 4; ++c) {
    const int cbase = c * CH;
    k_xp<<<c == 0 ? 60 : 48, 512, 0, stream>>>(
        (u16*)(ws + o_embx), doc_lens, query_lens,
        w_ih_f, b_ih_f, b_hh_f, w_ih_b, b_ih_b, b_hh_b,
        (float*)(ws + o_xpd), (float*)(ws + o_xpq), cbase);
    k_rec<<<c == 0 ? 48 : 24, 256, 0, stream>>>(
        (float*)(ws + o_xpd), (float*)(ws + o_xpq), doc_lens, query_lens,
        w_hh_f, b_hh_f, w_hh_b, b_hh_b,
        (u16*)(ws + o_doch), (u16*)(ws + o_qh),
        (u16*)(ws + o_hall), (float*)(ws + o_hst), cbase, c == 0 ? 1 : 0);
  }
  k_scores<<<512, 256, 0, stream>>>((u16*)(ws + o_doch), (u16*)(ws + o_qh), doc_lens, query_lens,
                                    (float*)(ws + o_SM), (float*)(ws + o_rmax), (float*)(ws + o_rsum));
  k_cols<<<32, 256, 0, stream>>>((float*)(ws + o_SM), (float*)(ws + o_rmax), (float*)(ws + o_rsum),
                                 doc_lens, query_lens,
                                 (float*)(ws + o_cmax), (float*)(ws + o_csum), (float*)(ws + o_bav));
  k_s<<<128, 256, 0, stream>>>((float*)(ws + o_SM), (float*)(ws + o_cmax), (float*)(ws + o_csum),
                               (float*)(ws + o_bav), doc_lens, query_lens, documents, answers,
                               (float*)(ws + o_sc), (float*)(ws + o_ctk), dout);
  k_pred<<<32, 256, 0, stream>>>((float*)(ws + o_sc), (float*)(ws + o_ctk), dout);
}

// Round 16
// 5283.393 us; speedup vs baseline: 1.1999x; 1.1999x over previous
//
#include <hip/hip_runtime.h>
#include <hip/hip_bf16.h>
#include <stdint.h>

#define EPSV 1e-12f
#define NB 32
#define DD 1024
#define QQ 64
#define EE 384
#define HH 384
#define NW 12    // workgroups per (corpus,dir) recurrence group
#define CH 256   // doc chunk length (steps) per launch
#define XPBUF ((size_t)2 * CH * 36864)   // floats per xp buffer (2 dirs)

typedef __attribute__((ext_vector_type(4))) float f32x4;
typedef __attribute__((ext_vector_type(8))) __bf16 bf16x8;
typedef __attribute__((ext_vector_type(4))) unsigned short u16x4;
typedef __attribute__((ext_vector_type(4))) int i32x4;
typedef unsigned short u16;

static __device__ __forceinline__ u16 f2bf(float f) {
  union { float f; uint32_t u; } v; v.f = f;
  uint32_t u = v.u;
  return (u16)((u + 0x7fffu + ((u >> 16) & 1u)) >> 16);  // RNE
}

static __device__ __forceinline__ f32x4 MFMA(bf16x8 a, bf16x8 b, f32x4 c) {
  return __builtin_amdgcn_mfma_f32_16x16x32_bf16(a, b, c, 0, 0, 0);
}

static __device__ __forceinline__ bf16x8 ldw8(const float* p) {
  float4 a = *(const float4*)p;
  float4 b = *(const float4*)(p + 4);
  union { u16 e[8]; bf16x8 v; } u;
  u.e[0] = f2bf(a.x); u.e[1] = f2bf(a.y); u.e[2] = f2bf(a.z); u.e[3] = f2bf(a.w);
  u.e[4] = f2bf(b.x); u.e[5] = f2bf(b.y); u.e[6] = f2bf(b.z); u.e[7] = f2bf(b.w);
  return u.v;
}

// device-scope (L3-coherent) ops — proven R3/R7/R12
static __device__ __forceinline__ void st_short_sc(u16* p, u16 v) {
  asm volatile("global_store_short %0, %1, off sc1" :: "v"(p), "v"((uint32_t)v) : "memory");
}
static __device__ __forceinline__ void ld_b128_sc(const u16* p, i32x4& d) {
  asm volatile("global_load_dwordx4 %0, %1, off sc1" : "=v"(d) : "v"(p) : "memory");
}
static __device__ __forceinline__ void st_dword_sc(unsigned* p, unsigned v) {
  asm volatile("global_store_dword %0, %1, off sc1" :: "v"(p), "v"(v) : "memory");
}
static __device__ __forceinline__ void ld_tags(const unsigned* p, i32x4& a, i32x4& b, i32x4& c,
                                               i32x4& d, i32x4& e, i32x4& f) {
  asm volatile(
      "global_load_dwordx4 %0, %6, off sc1\n\t"
      "global_load_dwordx4 %1, %6, off offset:16 sc1\n\t"
      "global_load_dwordx4 %2, %6, off offset:32 sc1\n\t"
      "global_load_dwordx4 %3, %6, off offset:48 sc1\n\t"
      "global_load_dwordx4 %4, %6, off offset:64 sc1\n\t"
      "global_load_dwordx4 %5, %6, off offset:80 sc1\n\t"
      "s_waitcnt vmcnt(0)"
      : "=&v"(a), "=&v"(b), "=&v"(c), "=&v"(d), "=&v"(e), "=&v"(f)
      : "v"(p) : "memory");
}

// ---------------- embedding gather ----------------
__global__ __launch_bounds__(256) void k_emb(const int* __restrict__ doc, const int* __restrict__ qry,
                                             const float* __restrict__ emb, u16* __restrict__ embx) {
  int i = blockIdx.x * 256 + threadIdx.x;
  int row = i / 96, e4 = i - row * 96;
  int tok = (row < NB * DD) ? doc[row] : qry[row - NB * DD];
  float4 v = ((const float4*)(emb + (size_t)tok * EE))[e4];
  u16x4 o; o.x = f2bf(v.x); o.y = f2bf(v.y); o.z = f2bf(v.z); o.w = f2bf(v.w);
  *(u16x4*)(embx + (size_t)row * EE + e4 * 4) = o;
}

// ---------------- standalone xp (chunk 0 doc + full q), R4/R12-proven verbatim ----------------
__global__ __launch_bounds__(512, 2) void k_xp(
    const u16* __restrict__ embx, const int* __restrict__ doc_lens, const int* __restrict__ q_lens,
    const float* __restrict__ w_ih_f, const float* __restrict__ b_ih_f, const float* __restrict__ b_hh_f,
    const float* __restrict__ w_ih_b, const float* __restrict__ b_ih_b, const float* __restrict__ b_hh_b,
    float* __restrict__ xpd, float* __restrict__ xpq, int cbase) {
  __shared__ int lensh[32];
  const int gx = blockIdx.x;
  int corpus, d2, jblk, tch;
  if (gx < 48) { corpus = 0; d2 = gx / 24; int rem = gx % 24; jblk = rem / 4; tch = rem % 4; }
  else { corpus = 1; int g2 = gx - 48; d2 = g2 / 6; jblk = g2 % 6; tch = 0; }
  const int T = corpus ? QQ : DD;
  const int* lens = corpus ? q_lens : doc_lens;
  const float* w_ih = d2 ? w_ih_b : w_ih_f;
  const float* b_ih = d2 ? b_ih_b : b_ih_f;
  const float* b_hh = d2 ? b_hh_b : b_hh_f;
  const u16* exb = embx + (corpus ? (size_t)NB * DD * EE : 0);
  float* xpg = corpus ? (xpq + (size_t)d2 * QQ * 36864) : (xpd + (size_t)d2 * CH * 36864);
  const int tid = threadIdx.x;
  if (tid < 32) lensh[tid] = lens[tid];
  __syncthreads();
  const int lane = tid & 63, wv = tid >> 6;
  const int wslot = wv >> 1, mt = wv & 1;
  const int col = lane & 15, khi = lane >> 4;
  const int jg = jblk * 64 + wslot * 16 + col;
  const float br = b_ih[jg] + b_hh[jg];
  const float bz = b_ih[384 + jg] + b_hh[384 + jg];
  const float bn = b_ih[768 + jg];
  bf16x8 Wr[12], Wz[12], Wn[12];
#pragma unroll
  for (int ks = 0; ks < 12; ++ks) {
    Wr[ks] = ldw8(w_ih + (size_t)jg * 384 + ks * 32 + khi * 8);
    Wz[ks] = ldw8(w_ih + (size_t)(384 + jg) * 384 + ks * 32 + khi * 8);
    Wn[ks] = ldw8(w_ih + (size_t)(768 + jg) * 384 + ks * 32 + khi * 8);
  }
  const int b_a = mt * 16 + col;
  const int lenb = lensh[b_a];
  const int bh0 = mt * 16 + khi * 4;
  for (int tt = 0; tt < 64; ++tt) {
    const int s_lc = tch * 64 + tt;
    const int s_g = corpus ? s_lc : (cbase + s_lc);
    const int trow = d2 ? ((s_g < lenb) ? (lenb - 1 - s_g) : s_g) : s_g;
    const u16* ap = exb + ((size_t)b_a * T + trow) * EE + khi * 8;
    bf16x8 A[12];
#pragma unroll
    for (int ks = 0; ks < 12; ++ks) A[ks] = *(const bf16x8*)(ap + ks * 32);
    f32x4 ar{0.f, 0.f, 0.f, 0.f}, az = ar, an = ar;
#pragma unroll
    for (int ks = 0; ks < 12; ++ks) {
      ar = MFMA(A[ks], Wr[ks], ar);
      az = MFMA(A[ks], Wz[ks], az);
      an = MFMA(A[ks], Wn[ks], an);
    }
    float* op = xpg + (size_t)s_lc * 36864 + (size_t)jg * 32 + bh0;
    f32x4 o0{ar[0] + br, ar[1] + br, ar[2] + br, ar[3] + br};
    f32x4 o1{az[0] + bz, az[1] + bz, az[2] + bz, az[3] + bz};
    f32x4 o2{an[0] + bn, an[1] + bn, an[2] + bn, an[3] + bn};
    *(f32x4*)op = o0;
    *(f32x4*)(op + 384 * 32) = o1;
    *(f32x4*)(op + 768 * 32) = o2;
  }
}

// ---------------- fused: recurrence (R12 verbatim) + next-chunk xp workers on spare CUs ----------------
// blocks [0, rec_blocks): R12 tag-protocol recurrence reading xp_rd.
// blocks [rec_blocks, ...): xp workers computing doc chunk (cbase+CH) into xp_wr (other buffer).
__global__ __launch_bounds__(256) void k_rec(
    const float* __restrict__ xp_rd, float* __restrict__ xp_wr, const float* __restrict__ xpq,
    const int* __restrict__ doc_lens, const int* __restrict__ q_lens,
    const float* __restrict__ w_hh_f, const float* __restrict__ b_hh_f,
    const float* __restrict__ w_hh_b, const float* __restrict__ b_hh_b,
    u16* __restrict__ doc_h, u16* __restrict__ q_h,
    u16* __restrict__ h_bc, unsigned* __restrict__ cnts, unsigned* __restrict__ tags,
    float* __restrict__ h_state,
    const u16* __restrict__ embx,
    const float* __restrict__ w_ih_f, const float* __restrict__ b_ih_f,
    const float* __restrict__ w_ih_b, const float* __restrict__ b_ih_b,
    int cbase, int first, int rec_blocks) {
  __shared__ u16 wfrag[36864];
  __shared__ int lensh[32];
  const int bid = blockIdx.x;
  const int tid = threadIdx.x;

  if (bid >= rec_blocks) {
    // ================= XP WORKER: doc chunk (cbase+CH) -> xp_wr =================
    const int e = bid - rec_blocks;
    const int d2 = e / 48;
    const int rem = e - d2 * 48;
    const int jb = rem >> 2, tch = rem & 3;
    const float* w_ih = d2 ? w_ih_b : w_ih_f;
    const float* b_ih = d2 ? b_ih_b : b_ih_f;
    const float* b_hh2 = d2 ? b_hh_b : b_hh_f;
    float* xpo = xp_wr + (size_t)d2 * CH * 36864;
    if (tid < 32) lensh[tid] = doc_lens[tid];
    __syncthreads();
    const int lane = tid & 63, wv = tid >> 6;
    const int wslot = wv >> 1, mt = wv & 1;
    const int col = lane & 15, khi = lane >> 4;
    const int jg = jb * 32 + wslot * 16 + col;
    const float br = b_ih[jg] + b_hh2[jg];
    const float bz = b_ih[384 + jg] + b_hh2[384 + jg];
    const float bn = b_ih[768 + jg];
    bf16x8 Wr[12], Wz[12], Wn[12];
#pragma unroll
    for (int ks = 0; ks < 12; ++ks) {
      Wr[ks] = ldw8(w_ih + (size_t)jg * 384 + ks * 32 + khi * 8);
      Wz[ks] = ldw8(w_ih + (size_t)(384 + jg) * 384 + ks * 32 + khi * 8);
      Wn[ks] = ldw8(w_ih + (size_t)(768 + jg) * 384 + ks * 32 + khi * 8);
    }
    const int b_a = mt * 16 + col;
    const int lenb = lensh[b_a];
    const int bh0 = mt * 16 + khi * 4;
    const int cb2 = cbase + CH;
    for (int tt = 0; tt < 64; ++tt) {
      const int s_lc = tch * 64 + tt;
      const int s_g = cb2 + s_lc;
      const int trow = d2 ? ((s_g < lenb) ? (lenb - 1 - s_g) : s_g) : s_g;
      const u16* ap = embx + ((size_t)b_a * DD + trow) * EE + khi * 8;
      bf16x8 A[12];
#pragma unroll
      for (int ks = 0; ks < 12; ++ks) A[ks] = *(const bf16x8*)(ap + ks * 32);
      f32x4 ar{0.f, 0.f, 0.f, 0.f}, az = ar, an = ar;
#pragma unroll
      for (int ks = 0; ks < 12; ++ks) {
        ar = MFMA(A[ks], Wr[ks], ar);
        az = MFMA(A[ks], Wz[ks], az);
        an = MFMA(A[ks], Wn[ks], an);
      }
      float* op = xpo + (size_t)s_lc * 36864 + (size_t)jg * 32 + bh0;
      f32x4 o0{ar[0] + br, ar[1] + br, ar[2] + br, ar[3] + br};
      f32x4 o1{az[0] + bz, az[1] + bz, az[2] + bz, az[3] + bz};
      f32x4 o2{an[0] + bn, an[1] + bn, an[2] + bn, an[3] + bn};
      *(f32x4*)op = o0;
      *(f32x4*)(op + 384 * 32) = o1;
      *(f32x4*)(op + 768 * 32) = o2;
    }
    return;
  }

  // ================= RECURRENCE (R12 verbatim) =================
  const int grp = bid / NW;
  const int wg = bid - grp * NW;
  const int corpus = grp >> 1, dir = grp & 1;
  const int T = corpus ? QQ : DD;
  const int nst = corpus ? QQ : CH;
  const int* lens = corpus ? q_lens : doc_lens;
  const float* w_hh = dir ? w_hh_b : w_hh_f;
  const float* b_hh = dir ? b_hh_b : b_hh_f;
  u16* out = corpus ? q_h : doc_h;
  const float* xpg = corpus ? (xpq + (size_t)dir * QQ * 36864) : (xp_rd + (size_t)dir * CH * 36864);
  u16* hb = h_bc + (size_t)grp * (2 * NB * HH);
  unsigned* cnt = cnts + (size_t)grp * 16;

  if (tid < 32) lensh[tid] = lens[tid];
  for (int idx = tid; idx < 36864; idx += 256) {
    int nt = idx / 6144;
    int rem = idx - nt * 6144;
    int ks = rem >> 9;
    int le = rem & 511;
    int lane_ = le >> 3, i = le & 7;
    int g = nt >> 1, js_ = nt & 1;
    int colw = lane_ & 15;
    int k = ks * 32 + (lane_ >> 4) * 8 + i;
    int rowg = g * 384 + wg * 32 + js_ * 16 + colw;
    wfrag[idx] = f2bf(w_hh[(size_t)rowg * 384 + k]);
  }
  if (first) {
    for (int idx = tid; idx < 1024; idx += 256) {
      int b = idx >> 5, jl_ = idx & 31;
      st_short_sc(hb + b * HH + wg * 32 + jl_, (u16)0);
    }
    asm volatile("s_waitcnt vmcnt(0)" ::: "memory");
  }
  __syncthreads();
  if (first) {
    if (tid == 0) {
      __hip_atomic_fetch_add(cnt, 1u, __ATOMIC_RELAXED, __HIP_MEMORY_SCOPE_AGENT);
      while (__hip_atomic_load(cnt, __ATOMIC_RELAXED, __HIP_MEMORY_SCOPE_AGENT) < (unsigned)NW)
        __builtin_amdgcn_s_sleep(1);
    }
    __syncthreads();
  }

  const int lane = tid & 63, wv = tid >> 6;
  const int mt = wv >> 1, js = wv & 1;
  const int col = lane & 15, khi = lane >> 4;
  const int jg = wg * 32 + js * 16 + col;
  const float bias_hn = b_hh[768 + jg];
  const int b_x = mt * 16 + col;
  const int bh0 = mt * 16 + khi * 4;
  int len_h[4];
#pragma unroll
  for (int r = 0; r < 4; ++r) len_h[r] = lensh[bh0 + r];
  u16* outp = out + (size_t)dir * HH + jg;
  f32x4 hprev;
#pragma unroll
  for (int r = 0; r < 4; ++r)
    hprev[r] = first ? 0.f : h_state[(size_t)grp * 12288 + (size_t)jg * 32 + (bh0 + r)];

  const unsigned* tagrow = tags + (size_t)grp * 64 + mt * 32;
  unsigned* tagp = tags + (size_t)grp * 64 + mt * 32 + (wg * 2 + js);

  auto umin2 = [](unsigned a, unsigned b) { return a < b ? a : b; };
  auto pollwait = [&](unsigned need) {
    while (true) {
      i32x4 t0, t1, t2, t3, t4, t5;
      ld_tags(tagrow, t0, t1, t2, t3, t4, t5);
      unsigned mn = 0xffffffffu;
#pragma unroll
      for (int k = 0; k < 4; ++k) {
        mn = umin2(mn, (unsigned)t0[k]); mn = umin2(mn, (unsigned)t1[k]);
        mn = umin2(mn, (unsigned)t2[k]); mn = umin2(mn, (unsigned)t3[k]);
        mn = umin2(mn, (unsigned)t4[k]); mn = umin2(mn, (unsigned)t5[k]);
      }
      if (mn >= need) break;
      __builtin_amdgcn_s_sleep(1);
    }
  };
  auto load_xp = [&](f32x4* x, int sl) {
    const float* xs = xpg + (size_t)sl * 36864;
#pragma unroll
    for (int g = 0; g < 3; ++g)
      x[g] = *(const f32x4*)(xs + ((size_t)(g * 384 + jg)) * 32 + bh0);
  };

  f32x4 xpA[3], xpB[3];
  load_xp(xpA, 0);

  auto step = [&](int sl, f32x4* xc, f32x4* xn) {
    const int s = cbase + sl;
    const int p = s & 1;
    const u16* rbuf = hb + p * (NB * HH);
    u16* wbuf = hb + (p ^ 1) * (NB * HH);
    pollwait((unsigned)s);
    i32x4 areg[12];
    const u16* ahp = rbuf + b_x * HH + khi * 8;
#pragma unroll
    for (int ks = 0; ks < 12; ++ks) ld_b128_sc(ahp + ks * 32, areg[ks]);
    asm volatile("s_waitcnt vmcnt(0)" ::: "memory");
    __builtin_amdgcn_sched_barrier(0);
    f32x4 acc_r{0.f, 0.f, 0.f, 0.f};
    f32x4 acc_z = acc_r, acc_nh = acc_r;
#pragma unroll
    for (int ks = 0; ks < 12; ++ks) {
      bf16x8 af = __builtin_bit_cast(bf16x8, areg[ks]);
      bf16x8 br = *(const bf16x8*)&wfrag[((js) * 12 + ks) * 512 + lane * 8];
      bf16x8 bz = *(const bf16x8*)&wfrag[((2 + js) * 12 + ks) * 512 + lane * 8];
      bf16x8 bn = *(const bf16x8*)&wfrag[((4 + js) * 12 + ks) * 512 + lane * 8];
      acc_r = MFMA(af, br, acc_r);
      acc_z = MFMA(af, bz, acc_z);
      acc_nh = MFMA(af, bn, acc_nh);
    }
    u16 hq[4];
#pragma unroll
    for (int r = 0; r < 4; ++r) {
      const int b = bh0 + r;
      float rg = 1.f / (1.f + __expf(-(acc_r[r] + xc[0][r])));
      float zg = 1.f / (1.f + __expf(-(acc_z[r] + xc[1][r])));
      float ng = tanhf(xc[2][r] + rg * (acc_nh[r] + bias_hn));
      float hn = (1.f - zg) * ng + zg * hprev[r];
      hprev[r] = hn;
      hq[r] = f2bf(hn);
      st_short_sc(wbuf + b * HH + jg, hq[r]);
    }
    asm volatile("s_waitcnt vmcnt(0)" ::: "memory");
    if (lane == 0) st_dword_sc(tagp, (unsigned)(s + 1));
    load_xp(xn, (sl + 1 < nst) ? (sl + 1) : sl);
#pragma unroll
    for (int r = 0; r < 4; ++r) {
      const int b = bh0 + r;
      const int len = len_h[r];
      const int tro = dir ? ((s < len) ? (len - 1 - s) : s) : s;
      outp[((size_t)b * T + tro) * (2 * HH)] = hq[r];
    }
  };

  for (int sl = 0; sl < nst; sl += 2) {
    step(sl, xpA, xpB);
    step(sl + 1, xpB, xpA);
  }
#pragma unroll
  for (int r = 0; r < 4; ++r)
    h_state[(size_t)grp * 12288 + (size_t)jg * 32 + (bh0 + r)] = hprev[r];
}

// ---------------- scores + row (q-axis) stats ----------------
__global__ __launch_bounds__(256) void k_scores(
    const u16* __restrict__ doc_h, const u16* __restrict__ q_h,
    const int* __restrict__ doc_lens, const int* __restrict__ q_lens,
    float* __restrict__ SM, float* __restrict__ rowmax, float* __restrict__ rowsum) {
  const int b = blockIdx.x >> 4, dblk = blockIdx.x & 15;
  const int tid = threadIdx.x, lane = tid & 63, wv = tid >> 6;
  const int col = lane & 15, khi = lane >> 4;
  const int dlen = doc_lens[b], qlen = q_lens[b];
  const u16* dp = doc_h + ((size_t)(b * DD + dblk * 64 + wv * 16 + col)) * (2 * HH) + khi * 8;
  const u16* qp = q_h + (size_t)b * QQ * (2 * HH);
  f32x4 acc[4];
#pragma unroll
  for (int nt = 0; nt < 4; ++nt) acc[nt] = f32x4{0.f, 0.f, 0.f, 0.f};
  for (int ks = 0; ks < 24; ++ks) {
    bf16x8 av = *(const bf16x8*)(dp + ks * 32);
#pragma unroll
    for (int nt = 0; nt < 4; ++nt) {
      bf16x8 bv = *(const bf16x8*)(qp + (size_t)(nt * 16 + col) * (2 * HH) + ks * 32 + khi * 8);
      acc[nt] = MFMA(av, bv, acc[nt]);
    }
  }
  const int d0 = dblk * 64 + wv * 16 + khi * 4;
  float* smb = SM + (size_t)b * DD * QQ;
#pragma unroll
  for (int r = 0; r < 4; ++r) {
    const int d = d0 + r;
    const bool dv = d < dlen;
    float v[4];
#pragma unroll
    for (int nt = 0; nt < 4; ++nt) {
      const int q = nt * 16 + col;
      v[nt] = (dv && q < qlen) ? acc[nt][r] : 0.f;
      smb[(size_t)d * QQ + q] = v[nt];
    }
    float mx = fmaxf(fmaxf(v[0], v[1]), fmaxf(v[2], v[3]));
#pragma unroll
    for (int off = 1; off < 16; off <<= 1) mx = fmaxf(mx, __shfl_xor(mx, off, 64));
    float sm = 0.f;
#pragma unroll
    for (int nt = 0; nt < 4; ++nt) {
      const int q = nt * 16 + col;
      if (dv && q < qlen) sm += __expf(v[nt] - mx);
    }
#pragma unroll
    for (int off = 1; off < 16; off <<= 1) sm += __shfl_xor(sm, off, 64);
    if (col == 0) { rowmax[b * DD + d] = mx; rowsum[b * DD + d] = sm; }
  }
}

// ---------------- column (d-axis) stats + beta_aver ----------------
__global__ __launch_bounds__(256) void k_cols(
    const float* __restrict__ SM, const float* __restrict__ rowmax, const float* __restrict__ rowsum,
    const int* __restrict__ doc_lens, const int* __restrict__ q_lens,
    float* __restrict__ colmax, float* __restrict__ colsum, float* __restrict__ bav) {
  const int b = blockIdx.x, tid = threadIdx.x;
  const int q = tid & 63, dg = tid >> 6;
  __shared__ float red[4][64];
  __shared__ float cmx[64];
  const float* smb = SM + (size_t)b * DD * QQ;
  float cm = -3.0e38f;
  for (int d = dg; d < DD; d += 4) cm = fmaxf(cm, smb[(size_t)d * QQ + q]);
  red[dg][q] = cm;
  __syncthreads();
  if (tid < 64) cmx[tid] = fmaxf(fmaxf(red[0][tid], red[1][tid]), fmaxf(red[2][tid], red[3][tid]));
  __syncthreads();
  const int dlen = doc_lens[b];
  const bool qv = q < q_lens[b];
  const float cmq = cmx[q];
  float cs = 0.f, ba = 0.f;
  for (int d = dg; d < DD; d += 4) {
    if (qv && d < dlen) {
      float v = smb[(size_t)d * QQ + q];
      cs += __expf(v - cmq);
      ba += __expf(v - rowmax[b * DD + d]) / (rowsum[b * DD + d] + EPSV);
    }
  }
  __syncthreads();
  red[dg][q] = cs;
  __syncthreads();
  float cst = 0.f;
  if (tid < 64) cst = red[0][tid] + red[1][tid] + red[2][tid] + red[3][tid];
  __syncthreads();
  red[dg][q] = ba;
  __syncthreads();
  if (tid < 64) {
    float bat = red[0][tid] + red[1][tid] + red[2][tid] + red[3][tid];
    colmax[b * QQ + tid] = cmx[tid];
    colsum[b * QQ + tid] = cst;
    bav[b * QQ + tid] = bat / (float)dlen;
  }
}

// ---------------- s = alpha @ beta_aver, probs, vocab scatter ----------------
__global__ __launch_bounds__(256) void k_s(
    const float* __restrict__ SM, const float* __restrict__ colmax, const float* __restrict__ colsum,
    const float* __restrict__ bav, const int* __restrict__ doc_lens, const int* __restrict__ q_lens,
    const int* __restrict__ documents, const int* __restrict__ answers,
    float* __restrict__ sc, float* __restrict__ cnt_tok, float* __restrict__ dout) {
  const int b = blockIdx.x >> 2, dblk = blockIdx.x & 3;
  const int tid = threadIdx.x;
  __shared__ float cm[64], cs[64], bv[64];
  __shared__ int qm[64];
  if (tid < 64) {
    cm[tid] = colmax[b * QQ + tid];
    cs[tid] = colsum[b * QQ + tid];
    bv[tid] = bav[b * QQ + tid];
    qm[tid] = (tid < q_lens[b]) ? 1 : 0;
  }
  __syncthreads();
  const int d = dblk * 256 + tid;
  const bool dv = d < doc_lens[b];
  const float* smr = SM + ((size_t)b * DD + d) * QQ;
  float sd = 0.f;
#pragma unroll
  for (int q = 0; q < 64; ++q) {
    float e = (dv && qm[q]) ? __expf(smr[q] - cm[q]) : 0.f;
    sd += e / (cs[q] + EPSV) * bv[q];
  }
  const int tok = documents[b * DD + d];
  if (tok == answers[b]) atomicAdd(&dout[b], sd);
  if (dv) {
    atomicAdd(&sc[(size_t)b * 50001 + tok], sd);
    atomicAdd(&cnt_tok[(size_t)b * 50001 + tok], 1.0f);
  }
}

// ---------------- first-max argmax over vocab ----------------
__global__ __launch_bounds__(256) void k_pred(
    const float* __restrict__ sc, const float* __restrict__ cnt_tok, float* __restrict__ dout) {
  const int b = blockIdx.x, tid = threadIdx.x;
  __shared__ float bvs[256];
  __shared__ int bis[256];
  float bvv = -3.0e38f;
  int bii = 0x7fffffff;
  for (int i = tid; i < 50001; i += 256) {
    if (cnt_tok[(size_t)b * 50001 + i] > 0.f) {
      float v = sc[(size_t)b * 50001 + i];
      if (v > bvv) { bvv = v; bii = i; }
    }
  }
  bvs[tid] = bvv;
  bis[tid] = bii;
  __syncthreads();
  for (int st = 128; st > 0; st >>= 1) {
    if (tid < st) {
      float v2 = bvs[tid + st];
      int i2 = bis[tid + st];
      if (v2 > bvs[tid] || (v2 == bvs[tid] && i2 < bis[tid])) { bvs[tid] = v2; bis[tid] = i2; }
    }
    __syncthreads();
  }
  if (tid == 0) dout[32 + b] = (float)bis[0];
}

extern "C" void kernel_launch(void* const* d_in, const int* in_sizes, int n_in,
                              void* d_out, int out_size, void* d_ws, size_t ws_size,
                              hipStream_t stream) {
  const int* documents = (const int*)d_in[0];
  const int* doc_lens = (const int*)d_in[1];
  const int* querys = (const int*)d_in[3];
  const int* query_lens = (const int*)d_in[4];
  const int* answers = (const int*)d_in[6];
  const float* emb = (const float*)d_in[7];
  const float* w_ih_f = (const float*)d_in[8];
  const float* w_hh_f = (const float*)d_in[9];
  const float* b_ih_f = (const float*)d_in[10];
  const float* b_hh_f = (const float*)d_in[11];
  const float* w_ih_b = (const float*)d_in[12];
  const float* w_hh_b = (const float*)d_in[13];
  const float* b_ih_b = (const float*)d_in[14];
  const float* b_hh_b = (const float*)d_in[15];
  float* dout = (float*)d_out;
  char* ws = (char*)d_ws;

  size_t o = 0;
  auto alloc = [&](size_t bytes) { size_t r = o; o += (bytes + 255) & ~(size_t)255; return r; };
  size_t o_embx = alloc((size_t)34816 * 384 * 2);
  size_t o_xpd  = alloc((size_t)2 * XPBUF * 4);   // two 75.5 MB buffers (double-buffered chunks)
  size_t o_xpq  = alloc((size_t)2 * QQ * 36864 * 4);
  size_t o_doch = alloc((size_t)NB * DD * 768 * 2);
  size_t o_qh   = alloc((size_t)NB * QQ * 768 * 2);
  size_t o_hbc  = alloc((size_t)4 * 2 * NB * HH * 2);
  size_t o_hst  = alloc((size_t)4 * HH * NB * 4);
  size_t o_cnt  = alloc((size_t)4 * 16 * 4);
  size_t o_tag  = alloc((size_t)4 * 64 * 4);
  size_t o_sync_end = o;
  size_t o_SM   = alloc((size_t)NB * DD * QQ * 4);
  size_t o_rmax = alloc((size_t)NB * DD * 4);
  size_t o_rsum = alloc((size_t)NB * DD * 4);
  size_t o_cmax = alloc((size_t)NB * QQ * 4);
  size_t o_csum = alloc((size_t)NB * QQ * 4);
  size_t o_bav  = alloc((size_t)NB * QQ * 4);
  size_t o_sc   = alloc((size_t)NB * 50001 * 4);
  size_t o_ctk  = alloc((size_t)NB * 50001 * 4);
  (void)ws_size; (void)in_sizes; (void)n_in; (void)out_size;

  hipMemsetAsync(ws + o_cnt, 0, o_sync_end - o_cnt, stream);
  hipMemsetAsync(ws + o_sc, 0, (o_ctk - o_sc) + (size_t)NB * 50001 * 4, stream);
  hipMemsetAsync(d_out, 0, 64 * sizeof(float), stream);

  k_emb<<<13056, 256, 0, stream>>>(documents, querys, emb, (u16*)(ws + o_embx));
  // chunk-0 doc xp (into buf 0) + full q xp
  k_xp<<<60, 512, 0, stream>>>((u16*)(ws + o_embx), doc_lens, query_lens,
                               w_ih_f, b_ih_f, b_hh_f, w_ih_b, b_ih_b, b_hh_b,
                               (float*)(ws + o_xpd), (float*)(ws + o_xpq), 0);
  for (int c = 0; c < 4; ++c) {
    const int rec_blocks = (c == 0) ? 48 : 24;
    const int xp_blocks = (c < 3) ? 96 : 0;
    float* xp_rd = (float*)(ws + o_xpd) + (size_t)(c & 1) * XPBUF;
    float* xp_wr = (float*)(ws + o_xpd) + (size_t)((c + 1) & 1) * XPBUF;
    k_rec<<<rec_blocks + xp_blocks, 256, 0, stream>>>(
        xp_rd, xp_wr, (float*)(ws + o_xpq), doc_lens, query_lens,
        w_hh_f, b_hh_f, w_hh_b, b_hh_b,
        (u16*)(ws + o_doch), (u16*)(ws + o_qh),
        (u16*)(ws + o_hbc), (unsigned*)(ws + o_cnt), (unsigned*)(ws + o_tag),
        (float*)(ws + o_hst),
        (u16*)(ws + o_embx), w_ih_f, b_ih_f, w_ih_b, b_ih_b,
        c * CH, c == 0 ? 1 : 0, rec_blocks);
  }
  k_scores<<<512, 256, 0, stream>>>((u16*)(ws + o_doch), (u16*)(ws + o_qh), doc_lens, query_lens,
                                    (float*)(ws + o_SM), (float*)(ws + o_rmax), (float*)(ws + o_rsum));
  k_cols<<<32, 256, 0, stream>>>((float*)(ws + o_SM), (float*)(ws + o_rmax), (float*)(ws + o_rsum),
                                 doc_lens, query_lens,
                                 (float*)(ws + o_cmax), (float*)(ws + o_csum), (float*)(ws + o_bav));
  k_s<<<128, 256, 0, stream>>>((float*)(ws + o_SM), (float*)(ws + o_cmax), (float*)(ws + o_csum),
                               (float*)(ws + o_bav), doc_lens, query_lens, documents, answers,
                               (float*)(ws + o_sc), (float*)(ws + o_ctk), dout);
  k_pred<<<32, 256, 0, stream>>>((float*)(ws + o_sc), (float*)(ws + o_ctk), dout);
}